// Round 2
// baseline (503.329 us; speedup 1.0000x reference)
//
#include <hip/hip_runtime.h>
#include <cstddef>

// Depthwise 7x7 conv, stride 1, pad 3, 4-fold rotational kernel symmetrization.
// x: [16,384,64,64] fp32, w: [384,1,7,7] fp32, out: [16,384,64,64] fp32.
//
// R3: LDS-FREE version. R2 post-mortem showed occupancy 31->63% changed nothing,
// and SQ_LDS_BANK_CONFLICT (44.5K cyc/CU = 18.5us of LDS-pipe stall) is
// structural: float4-aligned strip reads from a row-major tile always collide
// (any multiple-of-4 bank shift is absorbed by the cg coverage). The plane is
// only 16KB with ~2.5x reuse -- exactly what L1(32KB)/L2 serve for free.
//  - No __shared__ at all, no barrier: each thread reads its 12-float window
//    per input row directly from global (3x global_load_dwordx4, quarter-wave
//    runs of 272B). Halo -> clamped addresses + cndmask zeroing.
//  - Weights: wave-uniform scalar loads (c is uniform per block), symmetrized
//    in registers. No wsym staging.
//  - __launch_bounds__(256,6): VGPR cap ~85. R2's (256,8) cap of 64 forced the
//    compiler to 32 reported VGPRs (spill/remat) with >=45 live -- the likely
//    cause of VALUBusy pinned at 36%.
// Thread = 4 cols x 4 consecutive rows: 30 global loads, 784 FMA, 4 stores.

#define BLOCK 256

// --- compile-time C4 orbit table for the symmetrized 7x7 kernel (13 orbits) ---
constexpr int canon_of(int k) {
    const int i = k / 7, j = k % 7;
    const int a = i * 7 + j;
    const int b = j * 7 + (6 - i);
    const int c = (6 - i) * 7 + (6 - j);
    const int d = (6 - j) * 7 + i;
    int m = a;
    if (b < m) m = b;
    if (c < m) m = c;
    if (d < m) m = d;
    return m;
}
struct Tab { int cidx[49]; };
constexpr Tab build_tab() {
    Tab t{};
    int u = 0;
    for (int k = 0; k < 49; ++k)
        if (canon_of(k) == k) { t.cidx[k] = u; ++u; }
    for (int k = 0; k < 49; ++k) t.cidx[k] = t.cidx[canon_of(k)];
    return t;
}
constexpr Tab TAB = build_tab();

__global__ __launch_bounds__(BLOCK, 6) void dwconv7_sym_kernel(
    const float* __restrict__ x, const float* __restrict__ w,
    float* __restrict__ out, int C)
{
    const int plane = blockIdx.x;            // n*C + c
    const int c = plane % C;                 // wave-uniform
    const int tid = threadIdx.x;

    // --- symmetrized unique weights, straight to registers.
    //     wc + indices are wave-uniform -> scalar loads, L2-cached. ---
    const float* __restrict__ wc = w + c * 49;
    float wu[13];
    #pragma unroll
    for (int k = 0; k < 49; ++k) {
        if (canon_of(k) == k) {
            const int i = k / 7, j = k % 7;
            wu[TAB.cidx[k]] = 0.25f * (wc[i * 7 + j]
                                     + wc[j * 7 + (6 - i)]
                                     + wc[(6 - i) * 7 + (6 - j)]
                                     + wc[(6 - j) * 7 + i]);
        }
    }

    // --- thread = cols 4cg..4cg+3, out rows 4S..4S+3 ---
    const int cg = tid & 15;
    const int S  = tid >> 4;                 // 0..15
    const int x0 = 4 * cg;
    const float* __restrict__ xp = x + (size_t)plane * 4096;

    float acc[4][4];
    #pragma unroll
    for (int t = 0; t < 4; ++t)
        #pragma unroll
        for (int d = 0; d < 4; ++d) acc[t][d] = 0.f;

    #pragma unroll
    for (int ro = 0; ro < 10; ++ro) {
        const int row = 4 * S + ro - 3;      // input row, may be out of [0,64)
        const int rr  = (row < 0) ? 0 : (row > 63 ? 63 : row);   // safe address
        const float4* p = (const float4*)(xp + rr * 64 + x0);
        // Edge lanes read a discarded (zeroed) vector -- repoint their address
        // inward so no lane ever touches memory outside the tensor.
        const float4* pa = (cg == 0)  ? p : (p - 1);   // cols x0-4..x0-1
        const float4* pc = (cg == 15) ? p : (p + 1);   // cols x0+4..x0+7
        float4 a = *pa, b = *p, cc = *pc;
        if ((unsigned)row >= 64u) {          // halo row: contributes zero
            a.x = 0.f; a.y = 0.f; a.z = 0.f; a.w = 0.f;
            b.x = 0.f; b.y = 0.f; b.z = 0.f; b.w = 0.f;
            cc.x = 0.f; cc.y = 0.f; cc.z = 0.f; cc.w = 0.f;
        }
        if (cg == 0)  { a.x = 0.f; a.y = 0.f; a.z = 0.f; a.w = 0.f; }  // cols <0
        if (cg == 15) { cc.x = 0.f; cc.y = 0.f; cc.z = 0.f; }          // cols >=64
        const float r[12] = {a.x, a.y, a.z, a.w, b.x, b.y, b.z, b.w,
                             cc.x, cc.y, cc.z, cc.w};
        #pragma unroll
        for (int t = 0; t < 4; ++t) {
            if (t <= ro && ro <= t + 6) {          // constant after unroll
                const int i = ro - t;              // kernel row
                #pragma unroll
                for (int d = 0; d < 4; ++d)
                    #pragma unroll
                    for (int j = 0; j < 7; ++j)
                        acc[t][d] += r[d + j + 1] * wu[TAB.cidx[i * 7 + j]];
            }
        }
    }

    // --- direct stores: per wave instr = 4x 256B contiguous segments (dense) ---
    float4* __restrict__ op4 = (float4*)(out + (size_t)plane * 4096);
    #pragma unroll
    for (int t = 0; t < 4; ++t) {
        float4 v;
        v.x = acc[t][0]; v.y = acc[t][1]; v.z = acc[t][2]; v.w = acc[t][3];
        op4[(4 * S + t) * 16 + cg] = v;
    }
}

extern "C" void kernel_launch(void* const* d_in, const int* in_sizes, int n_in,
                              void* d_out, int out_size, void* d_ws, size_t ws_size,
                              hipStream_t stream) {
    const float* x = (const float*)d_in[0];
    const float* w = (const float*)d_in[1];
    float* out = (float*)d_out;

    const int planes = in_sizes[0] / 4096;   // N*C = 6144
    const int C = in_sizes[1] / 49;          // 384

    dwconv7_sym_kernel<<<dim3(planes), dim3(BLOCK), 0, stream>>>(x, w, out, C);
}

// Round 3
// 278.389 us; speedup vs baseline: 1.8080x; 1.8080x over previous
//
#include <hip/hip_runtime.h>
#include <cstddef>

// Depthwise 7x7 conv, stride 1, pad 3, 4-fold rotational kernel symmetrization.
// x: [16,384,64,64] fp32, w: [384,1,7,7] fp32, out: [16,384,64,64] fp32.
//
// R4: COLUMN-SWEEP, ZERO LDS. Post-mortems:
//  - R1/R2: occupancy 31%->63% changed nothing; LDS pipe ~50% duty with ~14
//    extra conflict cyc per ds_read_b128 (structural: every 16-lane group
//    covers all 32 banks, 4 groups -> 8-way). LDS round-trip never paid.
//  - R3: unrolled flat loop let the scheduler hoist 30 loads -> VGPR cap 85
//    -> scratch spill catastrophe (WRITE_SIZE 98MB -> 937MB).
// This version: thread = 4 cols x 16 out rows, sweeping input rows.
//  - Per row-step: 3x global_load_dwordx4 (256B runs; overlap L1-absorbed,
//    rows consumed immediately), 196 FMA into a 7-row pending-accumulator
//    register window (static lifetimes via full unroll), 1 store when an
//    out row completes.
//  - sched_barrier(0) per step: bounds lookahead to ONE row of loads in
//    flight (~392 FMA-cycles of latency cover) -- explicit software pipeline,
//    prevents the R3 hoist-then-spill failure.
//  - launch_bounds(256,4): cap 128, est live ~80. No tight cap -> no spills.
//  - Weights: readfirstlane-proven wave-uniform -> s_load, symmetrized in
//    regs. No LDS, no __syncthreads in the whole kernel.

#define BLOCK 256

// --- compile-time C4 orbit table for the symmetrized 7x7 kernel (13 orbits) ---
constexpr int canon_of(int k) {
    const int i = k / 7, j = k % 7;
    const int a = i * 7 + j;
    const int b = j * 7 + (6 - i);
    const int c = (6 - i) * 7 + (6 - j);
    const int d = (6 - j) * 7 + i;
    int m = a;
    if (b < m) m = b;
    if (c < m) m = c;
    if (d < m) m = d;
    return m;
}
struct Tab { int cidx[49]; };
constexpr Tab build_tab() {
    Tab t{};
    int u = 0;
    for (int k = 0; k < 49; ++k)
        if (canon_of(k) == k) { t.cidx[k] = u; ++u; }
    for (int k = 0; k < 49; ++k) t.cidx[k] = t.cidx[canon_of(k)];
    return t;
}
constexpr Tab TAB = build_tab();

__global__ __launch_bounds__(BLOCK, 4) void dwconv7_sym_kernel(
    const float* __restrict__ x, const float* __restrict__ w,
    float* __restrict__ out, int C)
{
    const int tid = threadIdx.x;
    const int cg = tid & 15;                 // col strip: cols 4cg..4cg+3
    const int q  = (tid >> 4) & 3;           // row quarter: out rows 16q..16q+15
    // p = wave id within block; provably wave-uniform via readfirstlane so the
    // weight loads become scalar (s_load) instead of 49 vector loads/thread.
    const int p  = __builtin_amdgcn_readfirstlane(tid >> 6);
    const int plane = blockIdx.x * 4 + p;    // n*C + c
    const int c = plane % C;

    // --- symmetrized unique weights -> 13 registers (scalar loads) ---
    const float* __restrict__ wc = w + c * 49;
    float wu[13];
    #pragma unroll
    for (int k = 0; k < 49; ++k) {
        if (canon_of(k) == k) {
            const int i = k / 7, j = k % 7;
            wu[TAB.cidx[k]] = 0.25f * (wc[i * 7 + j]
                                     + wc[j * 7 + (6 - i)]
                                     + wc[(6 - i) * 7 + (6 - j)]
                                     + wc[(6 - j) * 7 + i]);
        }
    }

    const int y0 = q << 4;
    const int x0 = cg << 2;
    const float* __restrict__ xb = x + (size_t)plane * 4096 + x0;
    float* __restrict__ ob = out + (size_t)plane * 4096 + y0 * 64 + x0;
    // Edge lanes re-point their halo load inward (value discarded via mask)
    // so no lane ever dereferences outside the tensor.
    const int offa = (cg == 0)  ? 0 : -4;    // cols x0-4..x0-1
    const int offc = (cg == 15) ? 0 :  4;    // cols x0+4..x0+7

    // Pending accumulators: acc[s] is live only for steps s..s+6 after unroll
    // (7 rows x 4 cols = 28 live regs at steady state; zero-init remats).
    float acc[16][4];
    #pragma unroll
    for (int s = 0; s < 16; ++s)
        #pragma unroll
        for (int d = 0; d < 4; ++d) acc[s][d] = 0.f;

    // --- prologue: load input row for step 0 (r = y0-3, clamped) ---
    float4 na, nb, nc;
    {
        const int r0 = y0 - 3;
        const int rr = r0 < 0 ? 0 : r0;      // y0-3 <= 45, no upper clamp
        const float* fb = xb + rr * 64;
        na = *(const float4*)(fb + offa);
        nb = *(const float4*)(fb);
        nc = *(const float4*)(fb + offc);
    }

    #pragma unroll
    for (int ro = 0; ro < 22; ++ro) {
        float4 a = na, b = nb, cv = nc;
        const int rcur = y0 + ro - 3;        // input row this step (may be OOB)

        // issue next row's loads now; FMAs below cover their latency
        if (ro < 21) {
            const int rn = y0 + ro - 2;
            const int rr = rn < 0 ? 0 : (rn > 63 ? 63 : rn);
            const float* fb = xb + rr * 64;
            na = *(const float4*)(fb + offa);
            nb = *(const float4*)(fb);
            nc = *(const float4*)(fb + offc);
        }

        // halo masking: OOB rows contribute zero; col edges zero their flanks
        if ((unsigned)rcur >= 64u) {
            a.x = 0.f; a.y = 0.f; a.z = 0.f; a.w = 0.f;
            b.x = 0.f; b.y = 0.f; b.z = 0.f; b.w = 0.f;
            cv.x = 0.f; cv.y = 0.f; cv.z = 0.f; cv.w = 0.f;
        }
        if (cg == 0)  { a.y = 0.f; a.z = 0.f; a.w = 0.f; }   // a.x unused
        if (cg == 15) { cv.x = 0.f; cv.y = 0.f; cv.z = 0.f; }

        const float r_[12] = {a.x, a.y, a.z, a.w, b.x, b.y, b.z, b.w,
                              cv.x, cv.y, cv.z, cv.w};

        // input row r contributes to out row y = r+3-i  ->  s = ro-i in [0,15]
        #pragma unroll
        for (int i = 0; i < 7; ++i) {
            if (i <= ro && ro - i <= 15) {   // constant after unroll
                const int s = ro - i;
                #pragma unroll
                for (int d = 0; d < 4; ++d)
                    #pragma unroll
                    for (int j = 0; j < 7; ++j)
                        acc[s][d] += r_[d + j + 1] * wu[TAB.cidx[i * 7 + j]];
            }
        }

        // out row y0+s complete after step s+6 -> store, freeing its regs
        if (ro >= 6) {
            const int s = ro - 6;
            float4 v;
            v.x = acc[s][0]; v.y = acc[s][1]; v.z = acc[s][2]; v.w = acc[s][3];
            *(float4*)(ob + s * 64) = v;
        }

        // scheduling fence: keeps exactly one row of loads in flight,
        // preventing the R3 hoist-everything-then-spill failure mode.
        __builtin_amdgcn_sched_barrier(0);
    }
}

extern "C" void kernel_launch(void* const* d_in, const int* in_sizes, int n_in,
                              void* d_out, int out_size, void* d_ws, size_t ws_size,
                              hipStream_t stream) {
    const float* x = (const float*)d_in[0];
    const float* w = (const float*)d_in[1];
    float* out = (float*)d_out;

    const int planes = in_sizes[0] / 4096;   // N*C = 6144
    const int C = in_sizes[1] / 49;          // 384

    dwconv7_sym_kernel<<<dim3(planes / 4), dim3(BLOCK), 0, stream>>>(x, w, out, C);
}

// Round 4
// 178.931 us; speedup vs baseline: 2.8130x; 1.5558x over previous
//
#include <hip/hip_runtime.h>
#include <cstddef>

// Depthwise 7x7 conv, stride 1, pad 3, 4-fold rotational kernel symmetrization.
// x: [16,384,64,64] fp32, w: [384,1,7,7] fp32, out: [16,384,64,64] fp32.
//
// R5: ZERO-LDS + DPP HALO EXCHANGE.
// Post-mortems R1-R4:
//  - LDS versions (66-70us): LDS pipe ~35us/CU (incl. 11.4M structural bank-
//    conflict cycles) serialized behind a staging barrier; occupancy not the
//    lever (31%->63% changed nothing).
//  - R3: 30 hoisted loads + VGPR cap 85 -> scratch spill catastrophe.
//  - R4: sched_barrier in the body blocked full unroll -> runtime-indexed acc
//    -> localMem spills (rule: runtime-indexed arrays go to scratch).
// This version eliminates the REASON for LDS/extra loads: the +-4-col halo is
// the neighboring lane's register. DPP row_shr:1 / row_shl:1 (VALU pipe,
// 1 instr) fetches it; bound_ctrl=1 zeroes at 16-lane row boundaries, which
// coincide exactly with image column edges. So:
//  - thread = 4 cols x 8 out rows; per input row: ONE aligned
//    global_load_dwordx4 (wave instr = 4x 256B dense aligned segments),
//    6 DPP movs, 112 FMA. 14 rows total.
//  - No LDS, no barrier, no scheduling intrinsics. Only 14 loads exist per
//    thread: even full hoisting fits (~120 VGPR) under the (256,2) cap of 256
//    -> spills impossible by construction.
//  - Weights: readfirstlane-uniform scalar loads -> SGPRs (free VALU operand).

#define BLOCK 256

// --- compile-time C4 orbit table for the symmetrized 7x7 kernel (13 orbits) ---
constexpr int canon_of(int k) {
    const int i = k / 7, j = k % 7;
    const int a = i * 7 + j;
    const int b = j * 7 + (6 - i);
    const int c = (6 - i) * 7 + (6 - j);
    const int d = (6 - j) * 7 + i;
    int m = a;
    if (b < m) m = b;
    if (c < m) m = c;
    if (d < m) m = d;
    return m;
}
struct Tab { int cidx[49]; };
constexpr Tab build_tab() {
    Tab t{};
    int u = 0;
    for (int k = 0; k < 49; ++k)
        if (canon_of(k) == k) { t.cidx[k] = u; ++u; }
    for (int k = 0; k < 49; ++k) t.cidx[k] = t.cidx[canon_of(k)];
    return t;
}
constexpr Tab TAB = build_tab();

// DPP lane shifts within 16-lane rows. bound_ctrl=1: invalid source lane -> 0,
// which implements the column-edge zero padding for free (lane rows of 16
// align exactly with cg = lane&15 and the 64-col image edges).
__device__ __forceinline__ float dpp_shr1(float v) {   // lane l <- lane l-1
    return __int_as_float(__builtin_amdgcn_update_dpp(
        0, __float_as_int(v), 0x111, 0xF, 0xF, true));
}
__device__ __forceinline__ float dpp_shl1(float v) {   // lane l <- lane l+1
    return __int_as_float(__builtin_amdgcn_update_dpp(
        0, __float_as_int(v), 0x101, 0xF, 0xF, true));
}

__global__ __launch_bounds__(BLOCK, 2) void dwconv7_sym_kernel(
    const float* __restrict__ x, const float* __restrict__ w,
    float* __restrict__ out, int C)
{
    const int tid = threadIdx.x;
    // 2 planes per block; p is wave-uniform (proven via readfirstlane) so the
    // weight path compiles to scalar loads into SGPRs.
    const int p = __builtin_amdgcn_readfirstlane(tid >> 7);
    const int plane = blockIdx.x * 2 + p;    // n*C + c
    const int c = plane % C;

    // --- symmetrized unique weights -> 13 scalar regs ---
    const float* __restrict__ wc = w + c * 49;
    float wu[13];
    #pragma unroll
    for (int k = 0; k < 49; ++k) {
        if (canon_of(k) == k) {
            const int i = k / 7, j = k % 7;
            wu[TAB.cidx[k]] = 0.25f * (wc[i * 7 + j]
                                     + wc[j * 7 + (6 - i)]
                                     + wc[(6 - i) * 7 + (6 - j)]
                                     + wc[(6 - j) * 7 + i]);
        }
    }

    const int idx = tid & 127;               // thread within plane
    const int cg = idx & 15;                 // col strip: cols 4cg..4cg+3
    const int S  = idx >> 4;                 // 0..7: out rows 8S..8S+7
    const int y0 = S << 3;
    const int x0 = cg << 2;
    const float* __restrict__ xp = x + (size_t)plane * 4096 + x0;
    float* __restrict__ ob = out + (size_t)plane * 4096 + y0 * 64 + x0;

    float acc[8][4];
    #pragma unroll
    for (int t = 0; t < 8; ++t)
        #pragma unroll
        for (int d = 0; d < 4; ++d) acc[t][d] = 0.f;

    // input rows y0-3 .. y0+10; row m contributes to out rows t in
    // [max(0,m-6), min(7,m)] via kernel row i = m - t. All indices static.
    #pragma unroll
    for (int m = 0; m < 14; ++m) {
        const int row = y0 - 3 + m;
        const int rr = row < 0 ? 0 : (row > 63 ? 63 : row);  // safe address
        float4 b = *(const float4*)(xp + rr * 64);
        if ((unsigned)row >= 64u) {          // top/bottom zero padding
            b.x = 0.f; b.y = 0.f; b.z = 0.f; b.w = 0.f;
        }
        // halo from neighbor lanes (zeros injected at image column edges)
        const float l1 = dpp_shr1(b.y);      // col x0-3
        const float l2 = dpp_shr1(b.z);      // col x0-2
        const float l3 = dpp_shr1(b.w);      // col x0-1
        const float h4 = dpp_shl1(b.x);      // col x0+4
        const float h5 = dpp_shl1(b.y);      // col x0+5
        const float h6 = dpp_shl1(b.z);      // col x0+6
        // r_[1..10] = cols x0-3 .. x0+6 (indices 0 and 11 never referenced)
        const float r_[12] = {0.f, l1, l2, l3, b.x, b.y, b.z, b.w,
                              h4, h5, h6, 0.f};
        #pragma unroll
        for (int t = 0; t < 8; ++t) {
            if (t <= m && m <= t + 6) {      // constant after unroll
                const int i = m - t;         // kernel row
                #pragma unroll
                for (int d = 0; d < 4; ++d)
                    #pragma unroll
                    for (int j = 0; j < 7; ++j)
                        acc[t][d] += r_[d + j + 1] * wu[TAB.cidx[i * 7 + j]];
            }
        }
    }

    // --- stores: per wave instr = 4x 256B dense aligned segments ---
    #pragma unroll
    for (int t = 0; t < 8; ++t) {
        float4 v;
        v.x = acc[t][0]; v.y = acc[t][1]; v.z = acc[t][2]; v.w = acc[t][3];
        *(float4*)(ob + t * 64) = v;
    }
}

extern "C" void kernel_launch(void* const* d_in, const int* in_sizes, int n_in,
                              void* d_out, int out_size, void* d_ws, size_t ws_size,
                              hipStream_t stream) {
    const float* x = (const float*)d_in[0];
    const float* w = (const float*)d_in[1];
    float* out = (float*)d_out;

    const int planes = in_sizes[0] / 4096;   // N*C = 6144
    const int C = in_sizes[1] / 49;          // 384

    dwconv7_sym_kernel<<<dim3(planes / 2), dim3(BLOCK), 0, stream>>>(x, w, out, C);
}